// Round 1
// baseline (113.175 us; speedup 1.0000x reference)
//
#include <hip/hip_runtime.h>
#include <hip/hip_bf16.h>

// out[m, f] = sum_e cos(x[m, e] + theta[e & 7]) * W[f, e]
// M = 65536, N = K = 512.  bf16 MFMA GEMM, A fused (add + cos + cvt) on the fly.

typedef __attribute__((ext_vector_type(8))) short short8;   // 8 x bf16 (4 VGPR)
typedef __attribute__((ext_vector_type(4))) float f32x4;    // MFMA acc frag

static __device__ __forceinline__ unsigned short f2bf(float f) {
    // round-to-nearest-even fp32 -> bf16 (bit math; no NaN inputs here)
    unsigned int b = __builtin_bit_cast(unsigned int, f);
    b += 0x7FFFu + ((b >> 16) & 1u);
    return (unsigned short)(b >> 16);
}

__global__ void cvt_w_kernel(const float* __restrict__ W,
                             unsigned short* __restrict__ Wb, int n4) {
    int i = blockIdx.x * blockDim.x + threadIdx.x;
    if (i < n4) {
        float4 v = reinterpret_cast<const float4*>(W)[i];
        ushort4 o;
        o.x = f2bf(v.x); o.y = f2bf(v.y); o.z = f2bf(v.z); o.w = f2bf(v.w);
        reinterpret_cast<ushort4*>(Wb)[i] = o;
    }
}

static constexpr int KDIM = 512;
static constexpr int NDIM = 512;
static constexpr int BM   = 64;
static constexpr int BK   = 64;
static constexpr int NSTEP = KDIM / BK;  // 8

template <bool PRECVT>
__global__ __launch_bounds__(512)
void fused_qgemm(const float* __restrict__ x, const float* __restrict__ theta,
                 const float* __restrict__ W, const unsigned short* __restrict__ Wb,
                 float* __restrict__ out) {
    // double-buffered A tile, bf16, XOR-swizzled rows (128 B pitch)
    __shared__ unsigned short lds[2][BM * BK];

    const int tid  = threadIdx.x;
    const int lane = tid & 63;
    const int wave = tid >> 6;            // 0..7 -> n0 = wave*64
    const int m0   = blockIdx.x * BM;
    const int n0   = wave * 64;

    float th[8];
#pragma unroll
    for (int j = 0; j < 8; ++j) th[j] = theta[j];

    // ---- staging map: thread -> (row = tid>>3, 8 k-elems at (tid&7)*8) ----
    const int srow = tid >> 3;            // 0..63
    const int scol = (tid & 7) * 8;       // k offset within tile
    const float* xp = x + (size_t)(m0 + srow) * KDIM + scol;
    // LDS byte addr for the 16B bf16x8 write, swizzled
    const int wbyte = srow * 128 + ((scol * 2) ^ ((srow & 7) << 4));

    // ---- fragment map ----
    const int frow = lane & 15;           // M (A) / N (B) / col (C)
    const int fkg  = lane >> 4;           // k-group 0..3

    f32x4 acc[4][4];
#pragma unroll
    for (int i = 0; i < 4; ++i)
#pragma unroll
        for (int j = 0; j < 4; ++j) acc[i][j] = (f32x4)(0.0f);

    // stage tile t's 8 values (already loaded into a,b) into lds[buf]
    auto pack_write = [&](int buf, const float4& a, const float4& b) {
        float v[8];
        *reinterpret_cast<float4*>(&v[0]) = a;
        *reinterpret_cast<float4*>(&v[4]) = b;
        short8 pk;
#pragma unroll
        for (int j = 0; j < 8; ++j)
            pk[j] = (short)f2bf(__builtin_cosf(v[j] + th[j]));  // e%8 == j here
        *reinterpret_cast<short8*>(reinterpret_cast<char*>(&lds[buf][0]) + wbyte) = pk;
    };

    // ---- prologue: stage tile 0 ----
    {
        float4 a = *reinterpret_cast<const float4*>(xp + 0);
        float4 b = *reinterpret_cast<const float4*>(xp + 4);
        pack_write(0, a, b);
    }
    __syncthreads();

    int cur = 0;
    for (int t = 0; t < NSTEP; ++t) {
        float4 na, nb;
        const bool more = (t + 1 < NSTEP);
        if (more) {  // issue next-tile global loads early; land under compute
            na = *reinterpret_cast<const float4*>(xp + (t + 1) * BK);
            nb = *reinterpret_cast<const float4*>(xp + (t + 1) * BK + 4);
        }

#pragma unroll
        for (int kf = 0; kf < BK / 32; ++kf) {
            short8 af[4];
#pragma unroll
            for (int i = 0; i < 4; ++i) {
                int row  = i * 16 + frow;
                int byte = row * 128 + (((kf * 32 + fkg * 8) * 2) ^ ((row & 7) << 4));
                af[i] = *reinterpret_cast<const short8*>(
                            reinterpret_cast<const char*>(&lds[cur][0]) + byte);
            }
            short8 bfr[4];
            const int kk = t * BK + kf * 32 + fkg * 8;
#pragma unroll
            for (int jn = 0; jn < 4; ++jn) {
                const int nn = n0 + jn * 16 + frow;
                if (PRECVT) {
                    bfr[jn] = *reinterpret_cast<const short8*>(Wb + (size_t)nn * KDIM + kk);
                } else {
                    float4 w0 = *reinterpret_cast<const float4*>(W + (size_t)nn * KDIM + kk);
                    float4 w1 = *reinterpret_cast<const float4*>(W + (size_t)nn * KDIM + kk + 4);
                    short8 t8;
                    t8[0] = (short)f2bf(w0.x); t8[1] = (short)f2bf(w0.y);
                    t8[2] = (short)f2bf(w0.z); t8[3] = (short)f2bf(w0.w);
                    t8[4] = (short)f2bf(w1.x); t8[5] = (short)f2bf(w1.y);
                    t8[6] = (short)f2bf(w1.z); t8[7] = (short)f2bf(w1.w);
                    bfr[jn] = t8;
                }
            }
#pragma unroll
            for (int i = 0; i < 4; ++i)
#pragma unroll
                for (int jn = 0; jn < 4; ++jn)
                    acc[i][jn] = __builtin_amdgcn_mfma_f32_16x16x32_bf16(
                        af[i], bfr[jn], acc[i][jn], 0, 0, 0);
        }

        if (more) pack_write(cur ^ 1, na, nb);  // other buffer: safe pre-barrier
        __syncthreads();
        cur ^= 1;
    }

    // ---- epilogue: C/D layout col=lane&15, row=(lane>>4)*4+reg ----
    float* op = out + (size_t)m0 * NDIM + n0;
#pragma unroll
    for (int i = 0; i < 4; ++i)
#pragma unroll
        for (int jn = 0; jn < 4; ++jn)
#pragma unroll
            for (int r = 0; r < 4; ++r)
                op[(size_t)(i * 16 + fkg * 4 + r) * NDIM + jn * 16 + frow] = acc[i][jn][r];
}

extern "C" void kernel_launch(void* const* d_in, const int* in_sizes, int n_in,
                              void* d_out, int out_size, void* d_ws, size_t ws_size,
                              hipStream_t stream) {
    const float* x     = (const float*)d_in[0];
    const float* theta = (const float*)d_in[1];
    const float* W     = (const float*)d_in[2];
    float* out         = (float*)d_out;

    const int M      = in_sizes[0] / KDIM;   // 65536
    const int wElems = in_sizes[2];          // 512*512

    if (ws_size >= (size_t)wElems * sizeof(unsigned short)) {
        unsigned short* Wb = (unsigned short*)d_ws;
        cvt_w_kernel<<<(wElems / 4 + 255) / 256, 256, 0, stream>>>(W, Wb, wElems / 4);
        fused_qgemm<true><<<M / BM, 512, 0, stream>>>(x, theta, W, Wb, out);
    } else {
        fused_qgemm<false><<<M / BM, 512, 0, stream>>>(x, theta, W, nullptr, out);
    }
}

// Round 2
// 95.083 us; speedup vs baseline: 1.1903x; 1.1903x over previous
//
#include <hip/hip_runtime.h>
#include <hip/hip_bf16.h>

// out[m, f] = sum_e cos(x[m, e] + theta[e & 7]) * W[f, e]
// M = 65536, N = K = 512.  bf16 MFMA GEMM, A = cos(x+theta) fused in staging.
//
// Structure: each block owns a 64x512 output stripe (full N). Stage the FULL
// 64x512 A-tile (bf16, XOR-swizzled) in 64 KB LDS with ONE barrier, then a
// barrier-free 16-step K loop (K_STEP=32) with 1-deep register prefetch of
// the B fragments (bf16 W copy in d_ws, L2-resident).

typedef __attribute__((ext_vector_type(8))) short short8;   // 8 x bf16 (4 VGPR)
typedef __attribute__((ext_vector_type(4))) float f32x4;    // MFMA acc frag

static constexpr int KD = 512;
static constexpr int ND = 512;
static constexpr int BM = 64;

static __device__ __forceinline__ unsigned short f2bf(float f) {
    unsigned int b = __builtin_bit_cast(unsigned int, f);
    b += 0x7FFFu + ((b >> 16) & 1u);
    return (unsigned short)(b >> 16);
}

// cos(a) via v_cos_f32: input in revolutions, explicit fract for range safety.
static __device__ __forceinline__ float fast_cos_rev(float rev) {
    float r = rev - floorf(rev);               // v_fract
    float c;
    asm("v_cos_f32 %0, %1" : "=v"(c) : "v"(r));
    return c;
}

__global__ void cvt_w_kernel(const float* __restrict__ W,
                             unsigned short* __restrict__ Wb, int n4) {
    int i = blockIdx.x * blockDim.x + threadIdx.x;
    if (i < n4) {
        float4 v = reinterpret_cast<const float4*>(W)[i];
        ushort4 o;
        o.x = f2bf(v.x); o.y = f2bf(v.y); o.z = f2bf(v.z); o.w = f2bf(v.w);
        reinterpret_cast<ushort4*>(Wb)[i] = o;
    }
}

template <bool PRECVT>
__global__ __launch_bounds__(512)
void fused_qgemm(const float* __restrict__ x, const float* __restrict__ theta,
                 const float* __restrict__ W, const unsigned short* __restrict__ Wb,
                 float* __restrict__ out) {
    __shared__ unsigned short Alds[BM * KD];   // 64 KB, row pitch 1024 B, swizzled

    const int tid  = threadIdx.x;
    const int lane = tid & 63;
    const int wave = tid >> 6;                 // 0..7 -> n0 = wave*64
    const int m0   = blockIdx.x * BM;
    const int n0   = wave * 64;

    constexpr float INV2PI = 0.15915493667125702f;
    float thC[8];
#pragma unroll
    for (int j = 0; j < 8; ++j) thC[j] = theta[j] * INV2PI;

    // ---- stage full A tile: thread -> row tid>>3, 8 chunks of 8 floats ----
    {
        const int srow = tid >> 3;
        const int sc0  = (tid & 7) * 8;
        const float* xp = x + (size_t)(m0 + srow) * KD + sc0;
        char* lb = reinterpret_cast<char*>(&Alds[0]) + srow * 1024;
        const int swz = (srow & 7) << 4;
#pragma unroll
        for (int c = 0; c < 8; ++c) {
            const int col = sc0 + c * 64;      // col % 8 == 0 -> theta idx = j
            float4 a = *reinterpret_cast<const float4*>(xp + c * 64);
            float4 b = *reinterpret_cast<const float4*>(xp + c * 64 + 4);
            float v[8];
            *reinterpret_cast<float4*>(&v[0]) = a;
            *reinterpret_cast<float4*>(&v[4]) = b;
            short8 pk;
#pragma unroll
            for (int j = 0; j < 8; ++j)
                pk[j] = (short)f2bf(fast_cos_rev(__builtin_fmaf(v[j], INV2PI, thC[j])));
            *reinterpret_cast<short8*>(lb + ((col * 2) ^ swz)) = pk;
        }
    }
    __syncthreads();

    // ---- fragment maps ----
    const int frow = lane & 15;                // M (A) / N (B) / col (C)
    const int fkg  = lane >> 4;                // k-group 0..3

    const unsigned short* wp[4];
    const float* wpf[4];
#pragma unroll
    for (int jn = 0; jn < 4; ++jn) {
        const size_t nn = (size_t)(n0 + jn * 16 + frow) * KD;
        wp[jn]  = Wb ? Wb + nn : nullptr;
        wpf[jn] = W + nn;
    }

    auto loadB = [&](int kf, short8* dst) {
        const int kk = kf * 32 + fkg * 8;
#pragma unroll
        for (int jn = 0; jn < 4; ++jn) {
            if (PRECVT) {
                dst[jn] = *reinterpret_cast<const short8*>(wp[jn] + kk);
            } else {
                float4 w0 = *reinterpret_cast<const float4*>(wpf[jn] + kk);
                float4 w1 = *reinterpret_cast<const float4*>(wpf[jn] + kk + 4);
                short8 t8;
                t8[0] = (short)f2bf(w0.x); t8[1] = (short)f2bf(w0.y);
                t8[2] = (short)f2bf(w0.z); t8[3] = (short)f2bf(w0.w);
                t8[4] = (short)f2bf(w1.x); t8[5] = (short)f2bf(w1.y);
                t8[6] = (short)f2bf(w1.z); t8[7] = (short)f2bf(w1.w);
                dst[jn] = t8;
            }
        }
    };
    auto loadA = [&](int kf, short8* dst) {
        const int kb = (kf * 32 + fkg * 8) * 2;
#pragma unroll
        for (int i = 0; i < 4; ++i) {
            const int row = i * 16 + frow;
            dst[i] = *reinterpret_cast<const short8*>(
                reinterpret_cast<const char*>(&Alds[0]) +
                row * 1024 + (kb ^ ((row & 7) << 4)));
        }
    };

    f32x4 acc[4][4];
#pragma unroll
    for (int i = 0; i < 4; ++i)
#pragma unroll
        for (int j = 0; j < 4; ++j) acc[i][j] = (f32x4)(0.0f);

    short8 bcur[4];
    loadB(0, bcur);

    for (int kf = 0; kf < 15; ++kf) {
        short8 bnext[4];
        loadB(kf + 1, bnext);                  // 1-deep L2 prefetch
        short8 af[4];
        loadA(kf, af);
#pragma unroll
        for (int i = 0; i < 4; ++i)
#pragma unroll
            for (int jn = 0; jn < 4; ++jn)
                acc[i][jn] = __builtin_amdgcn_mfma_f32_16x16x32_bf16(
                    af[i], bcur[jn], acc[i][jn], 0, 0, 0);
#pragma unroll
        for (int jn = 0; jn < 4; ++jn) bcur[jn] = bnext[jn];
    }
    {   // epilogue step kf = 15
        short8 af[4];
        loadA(15, af);
#pragma unroll
        for (int i = 0; i < 4; ++i)
#pragma unroll
            for (int jn = 0; jn < 4; ++jn)
                acc[i][jn] = __builtin_amdgcn_mfma_f32_16x16x32_bf16(
                    af[i], bcur[jn], acc[i][jn], 0, 0, 0);
    }

    // ---- C write: col = lane&15, row = (lane>>4)*4 + reg ----
    float* op = out + (size_t)m0 * ND + n0;
#pragma unroll
    for (int i = 0; i < 4; ++i)
#pragma unroll
        for (int jn = 0; jn < 4; ++jn)
#pragma unroll
            for (int r = 0; r < 4; ++r)
                op[(size_t)(i * 16 + fkg * 4 + r) * ND + jn * 16 + frow] = acc[i][jn][r];
}

extern "C" void kernel_launch(void* const* d_in, const int* in_sizes, int n_in,
                              void* d_out, int out_size, void* d_ws, size_t ws_size,
                              hipStream_t stream) {
    const float* x     = (const float*)d_in[0];
    const float* theta = (const float*)d_in[1];
    const float* W     = (const float*)d_in[2];
    float* out         = (float*)d_out;

    const int M      = in_sizes[0] / KD;       // 65536
    const int wElems = in_sizes[2];            // 512*512

    if (ws_size >= (size_t)wElems * sizeof(unsigned short)) {
        unsigned short* Wb = (unsigned short*)d_ws;
        cvt_w_kernel<<<(wElems / 4 + 255) / 256, 256, 0, stream>>>(W, Wb, wElems / 4);
        fused_qgemm<true><<<M / BM, 512, 0, stream>>>(x, theta, W, Wb, out);
    } else {
        fused_qgemm<false><<<M / BM, 512, 0, stream>>>(x, theta, W, nullptr, out);
    }
}